// Round 3
// baseline (85.506 us; speedup 1.0000x reference)
//
#include <hip/hip_runtime.h>
#include <cstddef>

#define EPS 1e-6f
constexpr float INV_SQRT_E = 0.6065306597126334f;  // exp(-0.5*THETA^2), THETA=1

// R16: two structural LDS cuts on the R15 base (ledger: SAD 45%, horiz 25%,
// staging+vertical 15% of LDS cycles).
//  A. slg plane DELETED: entropy's v*log(v) is computed on-the-fly inside a
//     single fused vertical pass (12 accums). Halves staging writes, halves
//     vertical reads, LDS 39936 -> 25600 B. D=1 does its 9 logs in-register.
//  B. SAD 2x2 pixel-quad walk for D=2,4: TWO FULL WAVES (4 row-pairs x 32
//     col-pairs = 128 threads) each walk (KS+1)^2 b32 taps serving 4 pixels
//     (R14 lesson: masked half-waves save nothing; full waves do).
//     D=4: 360->200, D=2: 120->72 wave-instrs. Column loop unroll(1) pins
//     ~10 loads in flight (R13/R14 spill lesson). Row stride bank-padded
//     (LW 96->100, 72->74) so the two half-waves hit disjoint bank sets.
//     D=3 keeps the R12 b32 pair-walk (odd stride).
// Config: block (64,8), TH=8, LDS 25,600 B -> 4 blocks/CU = 32 waves/CU.
template <int D>
__device__ __forceinline__ void body(const float* __restrict__ x,
                                     float* __restrict__ out,
                                     char* smem, int bc, int H, int W)
{
    constexpr int PAD = D * D;          // halo per side
    constexpr int KS  = 2 * D + 1;      // taps per axis
    constexpr int K   = KS * KS;        // patch size
    constexpr int TW  = 64, TH = 8;
    constexpr int LWD = TW + 2 * PAD;   // data width (even)
    constexpr int BPAD = (D == 4) ? 4 : ((D == 2) ? 2 : 0);   // bank pad
    constexpr int LW  = LWD + BPAD;     // stored row stride (even)
    constexpr int LH  = TH + 2 * PAD;
    constexpr int NED = LH * LWD;       // staged data elements (even)
    constexpr int NI2 = (NED + 1023) / 1024;
    constexpr float INVK = 1.0f / (float)K;
    constexpr float UNB  = (float)K / (float)(K - 1);

    float*  sx  = (float*)smem;                 // [LH*LW] v (cols >= LWD unused pad)
    float2* cs2 = (float2*)(sx + LH * LW);      // [TH*LW] {col_s, col_s2}
    float*  cs1 = (float*)(cs2 + TH * LW);      // [TH*LW] col_sl
    // Aliased exchange planes (cs2 dead after horizontal; needs 4096 B,
    // cs2 region >= 4736 B for D>=2).
    float*  muP  = (float*)cs2;                 // [TH*64]
    float*  sadP = muP + TH * 64;               // [TH*64]

    const int w0 = blockIdx.x * TW;
    const int h0 = blockIdx.y * TH;
    const float* xp = x + (size_t)bc * H * W;
    const int tid = threadIdx.y * 64 + threadIdx.x;

    // ---- Staging: element-pair global loads, b64 LDS writes (sx only). ----
    float v0b[NI2], v1b[NI2];
    #pragma unroll
    for (int i = 0; i < NI2; ++i) {
        const int e0 = 2 * (tid + i * 512);
        float v0 = 0.0f, v1 = 0.0f;
        if (e0 < NED) {
            const int r  = e0 / LWD;         // e0, LWD even -> cc even
            const int cc = e0 - r * LWD;
            const int gh = h0 - PAD + r;
            const int gw = w0 - PAD + cc;
            if (gh >= 0 && gh < H) {
                if constexpr ((PAD & 1) == 0) {
                    if (gw >= 0 && gw + 1 < W) {        // aligned float2 path
                        const float2 v = *(const float2*)&xp[gh * W + gw];
                        v0 = v.x; v1 = v.y;
                    } else {
                        if (gw >= 0 && gw < W)         v0 = xp[gh * W + gw];
                        if (gw + 1 >= 0 && gw + 1 < W) v1 = xp[gh * W + gw + 1];
                    }
                } else {
                    if (gw >= 0 && gw < W)         v0 = xp[gh * W + gw];
                    if (gw + 1 >= 0 && gw + 1 < W) v1 = xp[gh * W + gw + 1];
                }
            }
        }
        v0b[i] = v0; v1b[i] = v1;
    }
    #pragma unroll
    for (int i = 0; i < NI2; ++i) {
        const int e0 = 2 * (tid + i * 512);
        if (e0 < NED) {
            const int r  = e0 / LWD;
            const int cc = e0 - r * LWD;
            *(float2*)&sx[r * LW + cc] = make_float2(v0b[i], v1b[i]);
        }
    }
    __syncthreads();

    const int tx = threadIdx.x;
    const int ty = threadIdx.y;

    if constexpr (K <= 9) {
        // ---- D=1: single pass, taps in registers; logs in-register. ----
        const float* bx = sx + ty * LW + tx;
        float s = 0.f, s2 = 0.f, ta[K];
        #pragma unroll
        for (int mi = 0; mi < KS; ++mi)
            #pragma unroll
            for (int mj = 0; mj < KS; ++mj) {
                const float v = bx[mi * LW + mj];
                ta[mi * KS + mj] = v;
                s  += v;
                s2  = fmaf(v, v, s2);
            }
        const float mu = s * INVK;
        float sad = 0.f, sl = 0.f;
        #pragma unroll
        for (int i = 0; i < K; ++i) {
            sad += fabsf(ta[i] - mu);
            sl  += ta[i] * __logf(ta[i] + EPS);   // v=0 -> exactly 0
        }
        const float energy   = s2 * INVK;
        const float var      = fmaxf(energy - mu * mu, 0.f);
        const float sd       = sqrtf(var * UNB) + EPS;
        const float contrast = var / (sd * sd);
        const float entropy  = -sl * INVK;
        const float homog    = 1.f / (1.f + sad * INVK);
        const size_t fs = (size_t)H * W;
        const size_t ro = (size_t)(h0 + ty) * W;
        float* op = out + (size_t)bc * 4 * fs + w0 + tx;
        __builtin_nontemporal_store((contrast + EPS) * INV_SQRT_E, &op[0 * fs + ro]);
        __builtin_nontemporal_store((energy   + EPS) * INV_SQRT_E, &op[1 * fs + ro]);
        __builtin_nontemporal_store((entropy  + EPS) * INV_SQRT_E, &op[2 * fs + ro]);
        __builtin_nontemporal_store((homog    + EPS) * INV_SQRT_E, &op[3 * fs + ro]);
        return;
    } else {
        // ---- Vertical stage: fused single pass (s, s2, and on-the-fly
        //      v*log(v) for sl), column-PAIR float2 ladders. Row pairs:
        //  D=2: (0,2)(1,3)(4,6)(5,7)  D=3: (0,3)(1,4)(2,5)+{6,7}  D=4: (p,p+4)
        constexpr int HPAIRS = LWD / 2;           // data col-pairs only
        if (tid < 4 * HPAIRS) {
            const int p  = tid / HPAIRS;
            const int c2 = (tid - p * HPAIRS) * 2;
            if (!(D == 3 && p == 3)) {
                const int vA = (D == 2) ? ((p < 2) ? p : p + 2) : p;
                const int vB = vA + D;
                const float2* cx = (const float2*)(sx + vA * LW + c2);
                float sA0=0,sA1=0,qA0=0,qA1=0,lA0=0,lA1=0;
                float sB0=0,sB1=0,qB0=0,qB1=0,lB0=0,lB1=0;
                #pragma unroll
                for (int t = 0; t <= KS; ++t) {
                    const float2 v = cx[t * D * (LW / 2)];
                    const float g0 = v.x * __logf(v.x + EPS);
                    const float g1 = v.y * __logf(v.y + EPS);
                    if (t < KS) { sA0 += v.x; sA1 += v.y;
                                  qA0 = fmaf(v.x,v.x,qA0); qA1 = fmaf(v.y,v.y,qA1);
                                  lA0 += g0; lA1 += g1; }
                    if (t >= 1) { sB0 += v.x; sB1 += v.y;
                                  qB0 = fmaf(v.x,v.x,qB0); qB1 = fmaf(v.y,v.y,qB1);
                                  lB0 += g0; lB1 += g1; }
                }
                *(float4*)&cs2[vA * LW + c2] = make_float4(sA0, qA0, sA1, qA1);
                *(float4*)&cs2[vB * LW + c2] = make_float4(sB0, qB0, sB1, qB1);
                *(float2*)&cs1[vA * LW + c2] = make_float2(lA0, lA1);
                *(float2*)&cs1[vB * LW + c2] = make_float2(lB0, lB1);
            } else {            // D=3 leftover rows 6,7: independent col-pair walks
                #pragma unroll
                for (int rr = 6; rr <= 7; ++rr) {
                    const float2* cx = (const float2*)(sx + rr * LW + c2);
                    float s0=0,s1=0,q0=0,q1=0,l0=0,l1=0;
                    #pragma unroll
                    for (int mi = 0; mi < KS; ++mi) {
                        const float2 v = cx[mi * D * (LW / 2)];
                        s0 += v.x; s1 += v.y;
                        q0 = fmaf(v.x,v.x,q0); q1 = fmaf(v.y,v.y,q1);
                        l0 += v.x * __logf(v.x + EPS);
                        l1 += v.y * __logf(v.y + EPS);
                    }
                    *(float4*)&cs2[rr * LW + c2] = make_float4(s0, q0, s1, q1);
                    *(float2*)&cs1[rr * LW + c2] = make_float2(l0, l1);
                }
            }
        }
        __syncthreads();

        // ---- Horizontal stage: KS taps over column sums. ----
        float s = 0.f, s2 = 0.f, sl = 0.f;
        const float2* q2 = cs2 + ty * LW + tx;
        const float*  q1 = cs1 + ty * LW + tx;
        #pragma unroll
        for (int mj = 0; mj < KS; ++mj) {
            const float2 q = q2[mj * D];
            s += q.x; s2 += q.y; sl += q1[mj * D];
        }
        const float mu = s * INVK;
        __syncthreads();                 // cs reads done; muP may alias cs2

        muP[ty * 64 + tx] = mu;
        __syncthreads();

        // ---- SAD ----
        if constexpr ((D & 1) == 0) {
            // D even: 2x2 pixel-quad walk, TWO FULL WAVES (ty<2).
            // Thread -> (row-pair p, col-pair g): 4 x 32 = 128 threads.
            if (ty < 2) {
                const int p = ty * 2 + (tx >> 5);
                const int g = tx & 31;
                const int rA = (D == 2) ? ((p < 2) ? p : p + 2) : p;
                const int rB = rA + D;
                const int cA = (D == 2) ? (4 * (g >> 1) + (g & 1))
                                        : (8 * (g >> 2) + (g & 3));
                const int cB = cA + D;
                const float m00 = muP[rA * 64 + cA], m01 = muP[rA * 64 + cB];
                const float m10 = muP[rB * 64 + cA], m11 = muP[rB * 64 + cB];
                float a00 = 0.f, a01 = 0.f, a10 = 0.f, a11 = 0.f;
                const float* bp = sx + rA * LW + cA;
                // m = 0 column: cA pixels only
                #pragma unroll
                for (int t = 0; t <= KS; ++t) {
                    const float v = bp[t * D * LW];
                    if (t < KS) a00 += fabsf(v - m00);
                    if (t >= 1) a10 += fabsf(v - m10);
                }
                // interior columns: all four pixels (unroll(1) caps pressure)
                #pragma unroll 1
                for (int m = 1; m < KS; ++m) {
                    const float* cp = bp + m * D;
                    #pragma unroll
                    for (int t = 0; t <= KS; ++t) {
                        const float v = cp[t * D * LW];
                        if (t < KS) { a00 += fabsf(v - m00); a01 += fabsf(v - m01); }
                        if (t >= 1) { a10 += fabsf(v - m10); a11 += fabsf(v - m11); }
                    }
                }
                // m = KS column: cB pixels only
                {
                    const float* cp = bp + KS * D;
                    #pragma unroll
                    for (int t = 0; t <= KS; ++t) {
                        const float v = cp[t * D * LW];
                        if (t < KS) a01 += fabsf(v - m01);
                        if (t >= 1) a11 += fabsf(v - m11);
                    }
                }
                sadP[rA * 64 + cA] = a00; sadP[rA * 64 + cB] = a01;
                sadP[rB * 64 + cA] = a10; sadP[rB * 64 + cB] = a11;
            }
        } else {
            // D=3: R12 full-wave b32 pair-walk (odd stride; spill-safe).
            if (ty < 4) {
                const int o = ty;
                if (o != 3) {
                    const int rA = o;
                    const int rB = rA + D;
                    const float muA = muP[rA * 64 + tx];
                    const float muB = muP[rB * 64 + tx];
                    float sadA = 0.f, sadB = 0.f;
                    const float* bp = sx + rA * LW + tx;
                    #pragma unroll
                    for (int mj = 0; mj < KS; ++mj) {
                        const float* cp = bp + mj * D;
                        #pragma unroll
                        for (int t = 0; t <= KS; ++t) {
                            const float v = cp[t * D * LW];
                            if (t < KS) sadA += fabsf(v - muA);
                            if (t >= 1) sadB += fabsf(v - muB);
                        }
                    }
                    sadP[rA * 64 + tx] = sadA;
                    sadP[rB * 64 + tx] = sadB;
                } else {         // leftover rows 6,7: full K walks
                    #pragma unroll
                    for (int rr = 6; rr <= 7; ++rr) {
                        const float mur = muP[rr * 64 + tx];
                        const float* bp = sx + rr * LW + tx;
                        float sd = 0.f;
                        #pragma unroll
                        for (int mi = 0; mi < KS; ++mi)
                            #pragma unroll
                            for (int mj = 0; mj < KS; ++mj)
                                sd += fabsf(bp[mi * D * LW + mj * D] - mur);
                        sadP[rr * 64 + tx] = sd;
                    }
                }
            }
        }
        __syncthreads();
        const float sad = sadP[ty * 64 + tx];

        // ---- Epilogue. ----
        const float energy   = s2 * INVK;
        const float var      = fmaxf(energy - mu * mu, 0.f);
        const float sd       = sqrtf(var * UNB) + EPS;
        const float contrast = var / (sd * sd);
        const float entropy  = -sl * INVK;
        const float homog    = 1.f / (1.f + sad * INVK);
        const size_t fs = (size_t)H * W;
        const size_t ro = (size_t)(h0 + ty) * W;
        float* op = out + (size_t)bc * 4 * fs + w0 + tx;
        __builtin_nontemporal_store((contrast + EPS) * INV_SQRT_E, &op[0 * fs + ro]);
        __builtin_nontemporal_store((energy   + EPS) * INV_SQRT_E, &op[1 * fs + ro]);
        __builtin_nontemporal_store((entropy  + EPS) * INV_SQRT_E, &op[2 * fs + ro]);
        __builtin_nontemporal_store((homog    + EPS) * INV_SQRT_E, &op[3 * fs + ro]);
    }
}

__global__ __launch_bounds__(512, 8) void tex_fused(
    const float* __restrict__ x, float* __restrict__ out, int H, int W)
{
    extern __shared__ __align__(16) char smem[];
    const int dz = blockIdx.z & 3;       // dilation in fast bits: co-resident
    const int bc = blockIdx.z >> 2;      // blocks on a CU mix D1..D4
    const size_t per = (size_t)8 * 4 * H * W;
    switch (dz) {
        case 0: body<4>(x, out + 3 * per, smem, bc, H, W); break;
        case 1: body<3>(x, out + 2 * per, smem, bc, H, W); break;
        case 2: body<2>(x, out + 1 * per, smem, bc, H, W); break;
        default: body<1>(x, out + 0 * per, smem, bc, H, W); break;
    }
}

extern "C" void kernel_launch(void* const* d_in, const int* in_sizes, int n_in,
                              void* d_out, int out_size, void* d_ws, size_t ws_size,
                              hipStream_t stream) {
    const float* x = (const float*)d_in[0];
    float* out = (float*)d_out;

    const int H = 256, W = 256;
    // Per-D LDS (TH=8): sx LH*LW*4 + cs2 TH*LW*8 + cs1 TH*LW*4
    //   D=4: LH=40, LW=100: 16000 + 6400 + 3200 = 25600  (max) -> 4 blocks/CU
    //   D=3: LH=26, LW=82 :  8528 + 5248 + 2624 = 16400
    //   D=2: LH=16, LW=74 :  4736 + 4736 + 2368 = 11840
    //   D=1: LH=10, LW=66 :  2640 (register path; cs unused)
    const size_t smem_bytes = 25600;

    dim3 blk(64, 8, 1);
    dim3 grd(W / 64, H / 8, 8 * 4);      // 4 x-tiles, 32 y-tiles, (bc x dz)
    tex_fused<<<grd, blk, smem_bytes, stream>>>(x, out, H, W);
}

// Round 4
// 77.205 us; speedup vs baseline: 1.1075x; 1.1075x over previous
//
#include <hip/hip_runtime.h>
#include <cstddef>

#define EPS 1e-6f
constexpr float INV_SQRT_E = 0.6065306597126334f;  // exp(-0.5*THETA^2), THETA=1

// R17 = R15 verbatim (verified 77.3 us) + fast-math epilogue ONLY.
// R15/R16 post-mortem: a 13% LDS-instr cut was time-neutral and a 24% cut
// regressed (wave-count/ILP loss) => kernel is NOT LDS-issue bound; VALU
// ledger (~700 lane-ops/px, ~18 us) matches kernel time => VALU-bound.
// Cheapest big VALU item: epilogue's 2 IEEE divisions + sqrt per (px,D)
// (~25 lane-ops each) -> v_rcp_f32/v_sqrt_f32 (1-ulp; tolerance 3.9e-3,
// margin ~1e4x). Everything else untouched.
// Config: block (64,8), TH=8, LDS 39,936 B -> 4 blocks/CU = 32 waves/CU.
template <int D>
__device__ __forceinline__ void body(const float* __restrict__ x,
                                     float* __restrict__ out,
                                     char* smem, int bc, int H, int W)
{
    constexpr int PAD = D * D;          // halo per side
    constexpr int KS  = 2 * D + 1;      // taps per axis
    constexpr int K   = KS * KS;        // patch size
    constexpr int TW  = 64, TH = 8;
    constexpr int LW  = TW + 2 * PAD;   // always even
    constexpr int LH  = TH + 2 * PAD;
    constexpr int NE  = LH * LW;        // always even
    constexpr int NI2 = (NE + 1023) / 1024;
    constexpr float INVK = 1.0f / (float)K;
    constexpr float UNB  = (float)K / (float)(K - 1);

    float*  sx  = (float*)smem;                 // [NE] v
    float*  slg = sx + NE;                      // [NE] v*log(v+eps)
    float2* cs2 = (float2*)(slg + NE);          // [TH*LW] {col_s, col_s2}
    float*  cs1 = (float*)(cs2 + TH * LW);      // [TH*LW] col_sl
    // Aliased exchange planes (cs2 region is dead after the horizontal stage;
    // needs 4096 B, cs2 has >= 4608 B for D>=2).
    float*  muP  = (float*)cs2;                 // [TH*64]
    float*  sadP = muP + TH * 64;               // [TH*64]

    const int w0 = blockIdx.x * TW;
    const int h0 = blockIdx.y * TH;
    const float* xp = x + (size_t)bc * H * W;
    const int tid = threadIdx.y * 64 + threadIdx.x;

    // ---- Staging: batched global loads (element pairs), b64 LDS writes. ----
    float v0b[NI2], v1b[NI2];
    #pragma unroll
    for (int i = 0; i < NI2; ++i) {
        const int e0 = 2 * (tid + i * 512);
        float v0 = 0.0f, v1 = 0.0f;
        if (e0 < NE) {
            const int r  = e0 / LW;          // e0, LW even -> cc even
            const int cc = e0 - r * LW;
            const int gh = h0 - PAD + r;
            const int gw = w0 - PAD + cc;
            if (gh >= 0 && gh < H) {
                if constexpr ((PAD & 1) == 0) {
                    // gw even: aligned float2 global fast-path
                    if (gw >= 0 && gw + 1 < W) {
                        const float2 v = *(const float2*)&xp[gh * W + gw];
                        v0 = v.x; v1 = v.y;
                    } else {
                        if (gw >= 0 && gw < W)         v0 = xp[gh * W + gw];
                        if (gw + 1 >= 0 && gw + 1 < W) v1 = xp[gh * W + gw + 1];
                    }
                } else {
                    if (gw >= 0 && gw < W)         v0 = xp[gh * W + gw];
                    if (gw + 1 >= 0 && gw + 1 < W) v1 = xp[gh * W + gw + 1];
                }
            }
        }
        v0b[i] = v0; v1b[i] = v1;
    }
    #pragma unroll
    for (int i = 0; i < NI2; ++i) {
        const int e0 = 2 * (tid + i * 512);
        if (e0 < NE) {
            *(float2*)&sx[e0]  = make_float2(v0b[i], v1b[i]);
            *(float2*)&slg[e0] = make_float2(v0b[i] * __logf(v0b[i] + EPS),
                                             v1b[i] * __logf(v1b[i] + EPS));
        }
    }
    __syncthreads();

    const int tx = threadIdx.x;
    const int ty = threadIdx.y;

    if constexpr (K <= 9) {
        // ---- D=1: single pass, taps cached in registers. ----
        const float* bx = sx  + ty * LW + tx;
        const float* bl = slg + ty * LW + tx;
        float s = 0.f, s2 = 0.f, sl = 0.f, ta[K];
        #pragma unroll
        for (int mi = 0; mi < KS; ++mi)
            #pragma unroll
            for (int mj = 0; mj < KS; ++mj) {
                const float v = bx[mi * LW + mj];
                ta[mi * KS + mj] = v;
                s  += v;
                s2  = fmaf(v, v, s2);
                sl += bl[mi * LW + mj];
            }
        const float mu = s * INVK;
        float sad = 0.f;
        #pragma unroll
        for (int i = 0; i < K; ++i) sad += fabsf(ta[i] - mu);

        const float energy   = s2 * INVK;
        const float var      = fmaxf(energy - mu * mu, 0.f);
        const float sd       = __builtin_amdgcn_sqrtf(var * UNB) + EPS;
        const float contrast = var * __builtin_amdgcn_rcpf(sd * sd);
        const float entropy  = -sl * INVK;
        const float homog    = __builtin_amdgcn_rcpf(fmaf(sad, INVK, 1.0f));
        const size_t fs = (size_t)H * W;
        const size_t ro = (size_t)(h0 + ty) * W;
        float* op = out + (size_t)bc * 4 * fs + w0 + tx;
        __builtin_nontemporal_store((contrast + EPS) * INV_SQRT_E, &op[0 * fs + ro]);
        __builtin_nontemporal_store((energy   + EPS) * INV_SQRT_E, &op[1 * fs + ro]);
        __builtin_nontemporal_store((entropy  + EPS) * INV_SQRT_E, &op[2 * fs + ro]);
        __builtin_nontemporal_store((homog    + EPS) * INV_SQRT_E, &op[3 * fs + ro]);
        return;
    } else {
        // ---- Vertical stage: column-PAIR (b64) pair-walk, plane-split.
        //  Row pairs: D=2: (0,2)(1,3)(4,6)(5,7)  D=3: (0,3)(1,4)(2,5)+{6,7}
        //  D=4: (0,4)(1,5)(2,6)(3,7)
        constexpr int HW2 = LW / 2;
        if (tid < 4 * HW2) {
            const int p  = tid / HW2;
            const int c2 = (tid - p * HW2) * 2;
            if (!(D == 3 && p == 3)) {
                const int vA = (D == 2) ? ((p < 2) ? p : p + 2) : p;
                const int vB = vA + D;
                // pass 1: sx (sum + sumsq), 8 live accumulators
                const float2* cx = (const float2*)(sx + vA * LW + c2);
                float sA0=0,sA1=0,qA0=0,qA1=0,sB0=0,sB1=0,qB0=0,qB1=0;
                #pragma unroll
                for (int t = 0; t <= KS; ++t) {
                    const float2 v = cx[t * D * HW2];
                    if (t < KS) { sA0 += v.x; sA1 += v.y;
                                  qA0 = fmaf(v.x,v.x,qA0); qA1 = fmaf(v.y,v.y,qA1); }
                    if (t >= 1) { sB0 += v.x; sB1 += v.y;
                                  qB0 = fmaf(v.x,v.x,qB0); qB1 = fmaf(v.y,v.y,qB1); }
                }
                // pass 2: slg, 4 live accumulators
                const float2* cl = (const float2*)(slg + vA * LW + c2);
                float lA0=0,lA1=0,lB0=0,lB1=0;
                #pragma unroll
                for (int t = 0; t <= KS; ++t) {
                    const float2 g = cl[t * D * HW2];
                    if (t < KS) { lA0 += g.x; lA1 += g.y; }
                    if (t >= 1) { lB0 += g.x; lB1 += g.y; }
                }
                *(float4*)&cs2[vA * LW + c2] = make_float4(sA0, qA0, sA1, qA1);
                *(float4*)&cs2[vB * LW + c2] = make_float4(sB0, qB0, sB1, qB1);
                *(float2*)&cs1[vA * LW + c2] = make_float2(lA0, lA1);
                *(float2*)&cs1[vB * LW + c2] = make_float2(lB0, lB1);
            } else {            // D=3 leftover rows 6,7: independent col-pair walks
                #pragma unroll
                for (int rr = 6; rr <= 7; ++rr) {
                    const float2* cx = (const float2*)(sx  + rr * LW + c2);
                    const float2* cl = (const float2*)(slg + rr * LW + c2);
                    float s0=0,s1=0,q0=0,q1=0,l0=0,l1=0;
                    #pragma unroll
                    for (int mi = 0; mi < KS; ++mi) {
                        const float2 v = cx[mi * D * HW2];
                        const float2 g = cl[mi * D * HW2];
                        s0 += v.x; s1 += v.y;
                        q0 = fmaf(v.x,v.x,q0); q1 = fmaf(v.y,v.y,q1);
                        l0 += g.x; l1 += g.y;
                    }
                    *(float4*)&cs2[rr * LW + c2] = make_float4(s0, q0, s1, q1);
                    *(float2*)&cs1[rr * LW + c2] = make_float2(l0, l1);
                }
            }
        }
        __syncthreads();

        // ---- Horizontal stage: KS taps over column sums. ----
        float s = 0.f, s2 = 0.f, sl = 0.f;
        const float2* q2 = cs2 + ty * LW + tx;
        const float*  q1 = cs1 + ty * LW + tx;
        #pragma unroll
        for (int mj = 0; mj < KS; ++mj) {
            const float2 q = q2[mj * D];
            s += q.x; s2 += q.y; sl += q1[mj * D];
        }
        const float mu = s * INVK;
        __syncthreads();                 // cs reads done; muP may alias cs2

        muP[ty * 64 + tx] = mu;
        __syncthreads();

        // ---- SAD: full-wave b32 pair-walk (spill-safe). ----
        if (ty < 4) {
            const int o = ty;
            if (!(D == 3 && o == 3)) {
                const int rA = (D == 2) ? ((o < 2) ? o : o + 2) : o;
                const int rB = rA + D;
                const float muA = muP[rA * 64 + tx];
                const float muB = muP[rB * 64 + tx];
                float sadA = 0.f, sadB = 0.f;
                const float* bp = sx + rA * LW + tx;
                #pragma unroll
                for (int mj = 0; mj < KS; ++mj) {
                    const float* cp = bp + mj * D;
                    #pragma unroll
                    for (int t = 0; t <= KS; ++t) {
                        const float v = cp[t * D * LW];
                        if (t < KS) sadA += fabsf(v - muA);
                        if (t >= 1) sadB += fabsf(v - muB);
                    }
                }
                sadP[rA * 64 + tx] = sadA;
                sadP[rB * 64 + tx] = sadB;
            } else {             // D=3 leftover rows 6,7: full K walks
                #pragma unroll
                for (int rr = 6; rr <= 7; ++rr) {
                    const float mur = muP[rr * 64 + tx];
                    const float* bp = sx + rr * LW + tx;
                    float sd = 0.f;
                    #pragma unroll
                    for (int mi = 0; mi < KS; ++mi)
                        #pragma unroll
                        for (int mj = 0; mj < KS; ++mj)
                            sd += fabsf(bp[mi * D * LW + mj * D] - mur);
                    sadP[rr * 64 + tx] = sd;
                }
            }
        }
        __syncthreads();
        const float sad = sadP[ty * 64 + tx];

        // ---- Epilogue (fast-math: v_sqrt_f32 / v_rcp_f32, 1-ulp). ----
        const float energy   = s2 * INVK;
        const float var      = fmaxf(energy - mu * mu, 0.f);
        const float sd       = __builtin_amdgcn_sqrtf(var * UNB) + EPS;
        const float contrast = var * __builtin_amdgcn_rcpf(sd * sd);
        const float entropy  = -sl * INVK;
        const float homog    = __builtin_amdgcn_rcpf(fmaf(sad, INVK, 1.0f));
        const size_t fs = (size_t)H * W;
        const size_t ro = (size_t)(h0 + ty) * W;
        float* op = out + (size_t)bc * 4 * fs + w0 + tx;
        __builtin_nontemporal_store((contrast + EPS) * INV_SQRT_E, &op[0 * fs + ro]);
        __builtin_nontemporal_store((energy   + EPS) * INV_SQRT_E, &op[1 * fs + ro]);
        __builtin_nontemporal_store((entropy  + EPS) * INV_SQRT_E, &op[2 * fs + ro]);
        __builtin_nontemporal_store((homog    + EPS) * INV_SQRT_E, &op[3 * fs + ro]);
    }
}

__global__ __launch_bounds__(512, 8) void tex_fused(
    const float* __restrict__ x, float* __restrict__ out, int H, int W)
{
    extern __shared__ __align__(16) char smem[];
    const int dz = blockIdx.z & 3;       // dilation in fast bits: co-resident
    const int bc = blockIdx.z >> 2;      // blocks on a CU mix D1..D4
    const size_t per = (size_t)8 * 4 * H * W;
    switch (dz) {
        case 0: body<4>(x, out + 3 * per, smem, bc, H, W); break;
        case 1: body<3>(x, out + 2 * per, smem, bc, H, W); break;
        case 2: body<2>(x, out + 1 * per, smem, bc, H, W); break;
        default: body<1>(x, out + 0 * per, smem, bc, H, W); break;
    }
}

extern "C" void kernel_launch(void* const* d_in, const int* in_sizes, int n_in,
                              void* d_out, int out_size, void* d_ws, size_t ws_size,
                              hipStream_t stream) {
    const float* x = (const float*)d_in[0];
    float* out = (float*)d_out;

    const int H = 256, W = 256;
    // Per-D LDS (TH=8, PAD=D*D): 2 b32 planes LH*LW*8 + cs2 TH*LW*8 + cs1 TH*LW*4
    //   D=4: LH=40, LW=96: 30720 + 6144 + 3072 = 39936  (max) -> 4 blocks/CU
    //   D=3: LH=26, LW=82: 17056 + 5248 + 2624 = 24928
    //   D=2: LH=16, LW=72:  9216 + 4608 + 2304 = 16128
    //   D=1: LH=10, LW=66:  5280 (register path; cs unused)
    const size_t smem_bytes = 39936;

    dim3 blk(64, 8, 1);
    dim3 grd(W / 64, H / 8, 8 * 4);      // 4 x-tiles, 32 y-tiles, (bc x dz)
    tex_fused<<<grd, blk, smem_bytes, stream>>>(x, out, H, W);
}